// Round 11
// baseline (37.661 us; speedup 1.0000x reference)
//
#include <hip/hip_runtime.h>

// Problem constants
#define NL 64
#define NR 4096
#define NE 32
#define NF 64
#define NP 8

// RBF math:  rbf = exp(-((d - mu_e)*3.2)^2) = exp2(-(d*DSCALE - e*MUSTEP)^2)
#define DSCALE 3.8435917081166390f   // 3.2 * sqrt(log2(e))
#define MUSTEP 1.2398683f            // (10/31) * DSCALE
#define INVM   0.80653751f           // 1/MUSTEP
#define EPS3   3e-10f                // eps added per coordinate (3 coords)

typedef _Float16 f16x8 __attribute__((ext_vector_type(8)));
typedef __fp16   h16x2 __attribute__((ext_vector_type(2)));   // cvt_pkrtz result
typedef float    f32x4 __attribute__((ext_vector_type(4)));

#define NBLK 1024                    // 4 l-blocks x 256 r-blocks (full e-range!)
#define AROW 72                      // atn LDS row pitch bytes (36 halves; 16-bank spread)
#define WRED_B (256 * AROW)          // 18432

// ---- prep: lig_feat fp32 -> fp16 table, same [l][e][f] order (0.5 MB read) --
__global__ __launch_bounds__(256)
void ff_prep(const float* __restrict__ lig_feat, unsigned short* __restrict__ lig16) {
    const int tid = blockIdx.x * 256 + threadIdx.x;   // 32768 float4s
    const float4 v = ((const float4*)lig_feat)[tid];
    union { h16x2 h[2]; uint2 u; } pk;
    pk.h[0] = __builtin_amdgcn_cvt_pkrtz(v.x, v.y);
    pk.h[1] = __builtin_amdgcn_cvt_pkrtz(v.z, v.w);
    ((uint2*)lig16)[tid] = pk.u;
}

// ---- main: per block, FULL-e atn tile (16l x 16r x 32e) in LDS, then
//      windowed RBF (12 e's around each element's distance) ------------------
// ws layout: [0, 256KiB) = lig16 ; [256KiB, +32KiB) = partials [8][NBLK]
#define PART_B (NL * NE * NF * 2)

__global__ __launch_bounds__(256, 2)
void ff_main(const unsigned short* __restrict__ lig16,   // [64][32][64] fp16
             const float* __restrict__ rec_feat,         // [4096][32][64]
             const float* __restrict__ lig_coords,       // [8][64][3]
             const float* __restrict__ rec_coord,        // [4096][3]
             float* __restrict__ part)                   // [8][NBLK]
{
    __shared__ __align__(16) char smem[WRED_B + 128];

    const int t    = threadIdx.x;
    const int bid  = blockIdx.x;
    const int rb   = bid & 255;       // bid & bid+256 share XCD -> rec L2-shared
    const int lb   = bid >> 8;
    const int r0   = rb * 16;
    const int l0g  = lb * 16;
    const int lane = t & 63;
    const int wv   = t >> 6;
    const int cn   = lane & 15;       // MFMA col / frag row
    const int kg   = lane >> 4;       // k-group 0..3
    const int ew0  = wv * 8;          // this wave's e-range

    // ---- phase 1: MFMA, 8 e's per wave; atn -> LDS [l][r][e] fp16 ----
    const unsigned short* Ab = lig16 + ((l0g + cn) * NE + ew0) * NF + kg * 8;
    const float* Bb = rec_feat + ((r0 + cn) * NE + ew0) * NF + kg * 8;
    const int arow0 = (kg * 4 * 16 + cn) * AROW;   // + reg*16*AROW per C row

    auto atn_e = [&](int e) -> f32x4 {   // e relative to ew0 (compile-time)
        union { uint4 u; f16x8 v; } a0, a1;
        a0.u = *(const uint4*)(Ab + e * NF);
        a1.u = *(const uint4*)(Ab + e * NF + 32);
        const float4 f0 = *(const float4*)(Bb + e * NF);
        const float4 f1 = *(const float4*)(Bb + e * NF + 4);
        const float4 f2 = *(const float4*)(Bb + e * NF + 32);
        const float4 f3 = *(const float4*)(Bb + e * NF + 36);
        union { h16x2 h[4]; f16x8 v; } b0, b1;
        b0.h[0] = __builtin_amdgcn_cvt_pkrtz(f0.x, f0.y);
        b0.h[1] = __builtin_amdgcn_cvt_pkrtz(f0.z, f0.w);
        b0.h[2] = __builtin_amdgcn_cvt_pkrtz(f1.x, f1.y);
        b0.h[3] = __builtin_amdgcn_cvt_pkrtz(f1.z, f1.w);
        b1.h[0] = __builtin_amdgcn_cvt_pkrtz(f2.x, f2.y);
        b1.h[1] = __builtin_amdgcn_cvt_pkrtz(f2.z, f2.w);
        b1.h[2] = __builtin_amdgcn_cvt_pkrtz(f3.x, f3.y);
        b1.h[3] = __builtin_amdgcn_cvt_pkrtz(f3.z, f3.w);
        f32x4 C = {0.f, 0.f, 0.f, 0.f};
        C = __builtin_amdgcn_mfma_f32_16x16x32_f16(a0.v, b0.v, C, 0, 0, 0);
        C = __builtin_amdgcn_mfma_f32_16x16x32_f16(a1.v, b1.v, C, 0, 0, 0);
        return C;
    };

#pragma unroll
    for (int q = 0; q < 2; ++q) {     // two 4-e quads -> one b64 write per C row
        uint w0[4], w1[4];
        {
            const f32x4 C0 = atn_e(q * 4 + 0);
            const f32x4 C1 = atn_e(q * 4 + 1);
#pragma unroll
            for (int reg = 0; reg < 4; ++reg) {
                union { h16x2 h; uint u; } pw;
                pw.h = __builtin_amdgcn_cvt_pkrtz(C0[reg], C1[reg]);
                w0[reg] = pw.u;
            }
        }
        {
            const f32x4 C0 = atn_e(q * 4 + 2);
            const f32x4 C1 = atn_e(q * 4 + 3);
#pragma unroll
            for (int reg = 0; reg < 4; ++reg) {
                union { h16x2 h; uint u; } pw;
                pw.h = __builtin_amdgcn_cvt_pkrtz(C0[reg], C1[reg]);
                w1[reg] = pw.u;
            }
        }
#pragma unroll
        for (int reg = 0; reg < 4; ++reg) {
            uint2 d; d.x = w0[reg]; d.y = w1[reg];
            *(uint2*)(smem + arow0 + reg * (16 * AROW) + (ew0 / 4 + q) * 8) = d;
        }
    }
    __syncthreads();   // atn tile complete

    // ---- phase 2: windowed RBF; thread owns pair (l = t>>4, r = t&15) ----
    const int tl = t >> 4, tr = t & 15;
    const float rx = rec_coord[(r0 + tr) * 3 + 0];
    const float ry = rec_coord[(r0 + tr) * 3 + 1];
    const float rz = rec_coord[(r0 + tr) * 3 + 2];
    const __fp16* atnrow = (const __fp16*)(smem + (tl * 16 + tr) * AROW);
    const int gl = l0g + tl;

    float U[NP];
#pragma unroll
    for (int p = 0; p < NP; ++p) {
        const float lx = lig_coords[(p * NL + gl) * 3 + 0];
        const float ly = lig_coords[(p * NL + gl) * 3 + 1];
        const float lz = lig_coords[(p * NL + gl) * 3 + 2];
        const float dx = lx - rx, dy = ly - ry, dz = lz - rz;
        const float d2 = fmaf(dx, dx, fmaf(dy, dy, fmaf(dz, dz, EPS3)));
        const float ds = __builtin_amdgcn_sqrtf(d2) * DSCALE;
        // quad-aligned 12-e window: covers |z| <= ~4.96M; dropped terms < 2^-24
        int elo = (((int)(ds * INVM)) >> 2) * 4 - 4;
        elo = elo < 0 ? 0 : (elo > 20 ? 20 : elo);
        union { uint2 g[3]; __fp16 h[12]; } A;
        A.g[0] = *(const uint2*)(atnrow + elo);        // 8B-aligned (elo%4==0)
        A.g[1] = *(const uint2*)(atnrow + elo + 4);
        A.g[2] = *(const uint2*)(atnrow + elo + 8);
        const float zb = fmaf(-(float)elo, MUSTEP, ds);
        float acc = 0.f;
#pragma unroll
        for (int j = 0; j < 12; ++j) {                 // static idx: stays in regs
            const float z = zb - (float)j * MUSTEP;
            acc = fmaf((float)A.h[j],
                       __builtin_amdgcn_exp2f(fmaf(-z, z, 0.f)), acc);
        }
        U[p] = acc;
    }

    // ---- phase 3: reduce -> per-block partial ----
#pragma unroll
    for (int p = 0; p < NP; ++p) {
        float v = U[p];
        for (int off = 32; off; off >>= 1) v += __shfl_down(v, off, 64);
        U[p] = v;
    }
    float* wred = (float*)(smem + WRED_B);   // disjoint from atn region
    if (lane == 0) {
#pragma unroll
        for (int p = 0; p < NP; ++p) wred[wv * 8 + p] = U[p];
    }
    __syncthreads();
    if (t < NP)
        part[t * NBLK + bid] = wred[t] + wred[8 + t] + wred[16 + t] + wred[24 + t];
}

__global__ __launch_bounds__(512)
void ff_fin(const float* __restrict__ part,
            const float* __restrict__ w,
            const float* __restrict__ b,
            float* __restrict__ out) {
    const int t = threadIdx.x, lane = t & 63, p = t >> 6;
    float s = 0.f;
#pragma unroll
    for (int j = 0; j < NBLK / 256; ++j) {
        const float4 v = *(const float4*)&part[p * NBLK + j * 256 + lane * 4];
        s += (v.x + v.y) + (v.z + v.w);
    }
    for (int off = 32; off; off >>= 1) s += __shfl_down(s, off, 64);
    if (lane == 0) out[p] = fmaf(s, w[0], b[0]);
}

extern "C" void kernel_launch(void* const* d_in, const int* in_sizes, int n_in,
                              void* d_out, int out_size, void* d_ws, size_t ws_size,
                              hipStream_t stream) {
    const float* lig_feat   = (const float*)d_in[0];
    const float* rec_feat   = (const float*)d_in[1];
    const float* lig_coords = (const float*)d_in[2];
    const float* rec_coord  = (const float*)d_in[3];
    const float* weight     = (const float*)d_in[4];
    const float* bias       = (const float*)d_in[5];
    float* out = (float*)d_out;
    unsigned short* lig16 = (unsigned short*)d_ws;
    float* part = (float*)((char*)d_ws + PART_B);

    hipLaunchKernelGGL(ff_prep, dim3(128), dim3(256), 0, stream, lig_feat, lig16);
    hipLaunchKernelGGL(ff_main, dim3(NBLK), dim3(256), 0, stream,
                       lig16, rec_feat, lig_coords, rec_coord, part);
    hipLaunchKernelGGL(ff_fin, dim3(1), dim3(512), 0, stream,
                       part, weight, bias, out);
}

// Round 12
// 30.666 us; speedup vs baseline: 1.2281x; 1.2281x over previous
//
#include <hip/hip_runtime.h>

// Problem constants
#define NL 64
#define NR 4096
#define NE 32
#define NF 64
#define NP 8

// RBF math:  rbf = exp(-((d - mu_e)*3.2)^2) = exp2(-(d*DSCALE - e*MUSTEP)^2)
#define DSCALE 3.8435917081166390f   // 3.2 * sqrt(log2(e))
#define MUSTEP 1.2398683f            // (10/31) * DSCALE
#define EPS3   3e-10f                // eps added per coordinate (3 coords)

typedef _Float16 f16x8 __attribute__((ext_vector_type(8)));
typedef __fp16   h16x2 __attribute__((ext_vector_type(2)));   // cvt_pkrtz result
typedef float    f32x4 __attribute__((ext_vector_type(4)));

#define NBLK 2048                    // 8 e-blocks x 256 r-blocks: ALL co-resident
// ws layout: [0, 256KiB) = lig16 fp16 ; [256KiB, +64KiB) = partials [8][NBLK]
#define PART_B (NL * NE * NF * 2)

// LDS (17536 B -> 8 blocks/CU possible; VGPR 64 -> 8 blocks/CU):
//   REC   [4e][16r][128B swz] @0      : 8192 B, byte-in-row = (8*fq)^((r&7)*16)
//   COORD 64 l x 144B         @8192   : 9216 B (kg-stride 576B = bank16 -> 2-way, free)
//   WRED  32 f32              @17408  : 128 B
#define REC_B   0
#define COORD_B 8192
#define WRED_B  17408
#define CSTRIDE 144
#define LDS_SZ  17536

// ---- prep: lig_feat fp32 -> fp16 table, same [l][e][f] order ---------------
__global__ __launch_bounds__(256)
void ff_prep(const float* __restrict__ lig_feat, unsigned short* __restrict__ lig16) {
    const int tid = blockIdx.x * 256 + threadIdx.x;   // 32768 float4s
    const float4 v = ((const float4*)lig_feat)[tid];
    union { h16x2 h[2]; uint2 u; } pk;
    pk.h[0] = __builtin_amdgcn_cvt_pkrtz(v.x, v.y);
    pk.h[1] = __builtin_amdgcn_cvt_pkrtz(v.z, v.w);
    ((uint2*)lig16)[tid] = pk.u;
}

// ---- main ------------------------------------------------------------------
__global__ __launch_bounds__(256, 4)   // empirical: VGPR cap 64 -> 8 blocks/CU
void ff_main(const unsigned short* __restrict__ lig16,   // [64][32][64] fp16
             const float* __restrict__ rec_feat,         // [4096][32][64]
             const float* __restrict__ lig_coords,       // [8][64][3]
             const float* __restrict__ rec_coord,        // [4096][3]
             float* __restrict__ part)                   // [8][NBLK]
{
    __shared__ __align__(16) char smem[LDS_SZ];

    const int t    = threadIdx.x;
    const int bid  = blockIdx.x;
    const int rb   = bid & 255;
    const int eb   = bid >> 8;        // 8 e-blocks of 4
    const int r0   = rb * 16;
    const int e0   = eb * 4;
    const int lane = t & 63;
    const int wv   = t >> 6;
    const int l0   = wv * 16;
    const int cn   = lane & 15;       // MFMA col / frag row
    const int kg   = lane >> 4;       // k-group 0..3

    // ---- coords -> LDS [l: 144B stride][p: 16B] ----
#pragma unroll
    for (int j = 0; j < 6; ++j) {
        const int s = j * 256 + t;            // 0..1535 over [8p][64l][3c]
        const int p = s / 192;
        const int rem = s - p * 192;
        const int l = rem / 3, c = rem - l * 3;
        *(float*)(smem + COORD_B + l * CSTRIDE + p * 16 + c * 4) = lig_coords[s];
    }
    // ---- REC tile: 1 e at a time (8-reg transient keeps live-set under 64) ----
    const int srow = t >> 4, sfq = t & 15;
    const int rswz = (8 * sfq) ^ ((srow & 7) << 4);
    const float* recrow = &rec_feat[((r0 + srow) * NE + e0) * NF + sfq * 4];
#pragma unroll
    for (int e = 0; e < 4; ++e) {
        const float4 v = *(const float4*)(recrow + e * NF);
        union { h16x2 h[2]; uint2 u; } pk;
        pk.h[0] = __builtin_amdgcn_cvt_pkrtz(v.x, v.y);
        pk.h[1] = __builtin_amdgcn_cvt_pkrtz(v.z, v.w);
        *(uint2*)(smem + REC_B + e * 2048 + srow * 128 + rswz) = pk.u;
    }
    __syncthreads();   // coords + rec ready

    // ---- distances, packed fp16: dsp[reg] = 8 poses for l = l0+kg*4+reg ----
    const int rr = r0 + cn;
    const float rx = rec_coord[rr * 3 + 0];
    const float ry = rec_coord[rr * 3 + 1];
    const float rz = rec_coord[rr * 3 + 2];
    uint4 dsp[4];
#pragma unroll
    for (int reg = 0; reg < 4; ++reg) {
        const int l = l0 + kg * 4 + reg;
        float d[NP];
#pragma unroll
        for (int p = 0; p < NP; ++p) {
            const float4 lc = *(const float4*)(smem + COORD_B + l * CSTRIDE + p * 16);
            const float dx = lc.x - rx, dy = lc.y - ry, dz = lc.z - rz;
            const float d2 = fmaf(dx, dx, fmaf(dy, dy, fmaf(dz, dz, EPS3)));
            d[p] = __builtin_amdgcn_sqrtf(d2) * DSCALE;
        }
        union { h16x2 h[4]; uint4 u; } pk;
#pragma unroll
        for (int q = 0; q < 4; ++q)
            pk.h[q] = __builtin_amdgcn_cvt_pkrtz(d[2 * q], d[2 * q + 1]);
        dsp[reg] = pk.u;
    }

    // ---- main loop over 4 e's: A from fp16 table (L2-hot), B from LDS ----
    const unsigned short* ligb = lig16 + ((l0 + cn) * NE + e0) * NF + kg * 8;
    const int bsw = (cn & 7) << 4;
    const int b0o = REC_B + cn * 128 + ((kg * 16) ^ bsw);
    const int b1o = REC_B + cn * 128 + ((kg * 16 + 64) ^ bsw);

    float U[NP];
#pragma unroll
    for (int p = 0; p < NP; ++p) U[p] = 0.f;

#pragma unroll
    for (int ee = 0; ee < 4; ++ee) {
        union { uint4 u; f16x8 v; } a0, a1;
        a0.u = *(const uint4*)(ligb + ee * NF);
        a1.u = *(const uint4*)(ligb + ee * NF + 32);
        const f16x8 b0 = *(const f16x8*)(smem + b0o + ee * 2048);
        const f16x8 b1 = *(const f16x8*)(smem + b1o + ee * 2048);
        f32x4 C = {0.f, 0.f, 0.f, 0.f};
        C = __builtin_amdgcn_mfma_f32_16x16x32_f16(a0.v, b0, C, 0, 0, 0);
        C = __builtin_amdgcn_mfma_f32_16x16x32_f16(a1.v, b1, C, 0, 0, 0);

        const float mu = (float)(e0 + ee) * MUSTEP;
#pragma unroll
        for (int reg = 0; reg < 4; ++reg) {
            const float a = C[reg];
            union { uint4 u; __fp16 h[8]; } pk;
            pk.u = dsp[reg];
#pragma unroll
            for (int p = 0; p < NP; ++p) {
                const float z = (float)pk.h[p] - mu;
                U[p] = fmaf(a, __builtin_amdgcn_exp2f(fmaf(-z, z, 0.f)), U[p]);
            }
        }
    }

    // ---- reduce -> per-block partial ----
#pragma unroll
    for (int p = 0; p < NP; ++p) {
        float v = U[p];
        for (int off = 32; off; off >>= 1) v += __shfl_down(v, off, 64);
        U[p] = v;
    }
    float* wred = (float*)(smem + WRED_B);
    if (lane == 0) {
#pragma unroll
        for (int p = 0; p < NP; ++p) wred[wv * 8 + p] = U[p];
    }
    __syncthreads();
    if (t < NP)
        part[t * NBLK + bid] = wred[t] + wred[8 + t] + wred[16 + t] + wred[24 + t];
}

__global__ __launch_bounds__(512)
void ff_fin(const float* __restrict__ part,
            const float* __restrict__ w,
            const float* __restrict__ b,
            float* __restrict__ out) {
    const int t = threadIdx.x, lane = t & 63, p = t >> 6;
    float s = 0.f;
#pragma unroll
    for (int j = 0; j < NBLK / 256; ++j) {
        const float4 v = *(const float4*)&part[p * NBLK + j * 256 + lane * 4];
        s += (v.x + v.y) + (v.z + v.w);
    }
    for (int off = 32; off; off >>= 1) s += __shfl_down(s, off, 64);
    if (lane == 0) out[p] = fmaf(s, w[0], b[0]);
}

extern "C" void kernel_launch(void* const* d_in, const int* in_sizes, int n_in,
                              void* d_out, int out_size, void* d_ws, size_t ws_size,
                              hipStream_t stream) {
    const float* lig_feat   = (const float*)d_in[0];
    const float* rec_feat   = (const float*)d_in[1];
    const float* lig_coords = (const float*)d_in[2];
    const float* rec_coord  = (const float*)d_in[3];
    const float* weight     = (const float*)d_in[4];
    const float* bias       = (const float*)d_in[5];
    float* out = (float*)d_out;
    unsigned short* lig16 = (unsigned short*)d_ws;
    float* part = (float*)((char*)d_ws + PART_B);

    hipLaunchKernelGGL(ff_prep, dim3(128), dim3(256), 0, stream, lig_feat, lig16);
    hipLaunchKernelGGL(ff_main, dim3(NBLK), dim3(256), 0, stream,
                       lig16, rec_feat, lig_coords, rec_coord, part);
    hipLaunchKernelGGL(ff_fin, dim3(1), dim3(512), 0, stream,
                       part, weight, bias, out);
}